// Round 1
// baseline (1006.208 us; speedup 1.0000x reference)
//
#include <hip/hip_runtime.h>
#include <math.h>

// Problem constants
#define B 4
#define NPTS 300000
#define G 15
#define G3 3375            // 15^3
#define CONV_OUT 8         // spatial after stride-2 conv: 8
#define YELEMS (B*8*8*8*8) // 16384

__device__ __forceinline__ float eluf(float v) {
    return v > 0.0f ? v : expm1f(v);
}

// ---------------------------------------------------------------------------
// Stage 1: per-point features -> MLP -> scatter-max into scenes grid
// scenes layout: [B, 12, 15,15,15], channel = set*4 + c
// set 0 = inputs, 1 = goals, 2 = backgrounds  (concat order in reference)
// ---------------------------------------------------------------------------
__global__ __launch_bounds__(256)
void point_kernel(const float* __restrict__ P0,   // inputs
                  const float* __restrict__ P1,   // goals
                  const float* __restrict__ P2,   // backgrounds
                  const float* __restrict__ W1, const float* __restrict__ b1,
                  const float* __restrict__ W2, const float* __restrict__ b2,
                  const float* __restrict__ W3, const float* __restrict__ b3,
                  float* __restrict__ scenes)
{
    __shared__ float sW1[12*16], sb1[16], sW2[16*16], sb2[16], sW3[16*4], sb3[4];
    int tid = threadIdx.x;
    for (int i = tid; i < 192; i += 256) sW1[i] = W1[i];
    for (int i = tid; i < 256; i += 256) sW2[i] = W2[i];
    for (int i = tid; i < 64;  i += 256) sW3[i] = W3[i];
    if (tid < 16) { sb1[tid] = b1[tid]; sb2[tid] = b2[tid]; }
    if (tid < 4)  { sb3[tid] = b3[tid]; }
    __syncthreads();

    int set = blockIdx.y;
    const float* P = (set == 0) ? P0 : ((set == 1) ? P1 : P2);

    int idx = blockIdx.x * 256 + tid;
    if (idx >= B * NPTS) return;

    float px = P[idx*3 + 0];
    float py = P[idx*3 + 1];
    float pz = P[idx*3 + 2];

    const float HI = 14.9999f;  // GZ - 1e-4
    float cx = floorf(fminf(fmaxf(px, 0.0f), HI));
    float cy = floorf(fminf(fmaxf(py, 0.0f), HI));
    float cz = floorf(fminf(fmaxf(pz, 0.0f), HI));

    float x[12];
    x[0] = px - (cx + 0.5f); x[1] = py - (cy + 0.5f); x[2] = pz - (cz + 0.5f);
    x[3] = px - cx;          x[4] = py - cy;          x[5] = pz - cz;
    x[6] = px - (cx + 1.0f); x[7] = py - (cy + 1.0f); x[8] = pz - (cz + 1.0f);
    x[9]  = sqrtf(x[0]*x[0] + x[1]*x[1] + x[2]*x[2]);
    x[10] = sqrtf(x[3]*x[3] + x[4]*x[4] + x[5]*x[5]);
    x[11] = sqrtf(x[6]*x[6] + x[7]*x[7] + x[8]*x[8]);

    float h1[16];
#pragma unroll
    for (int j = 0; j < 16; ++j) {
        float s = sb1[j];
#pragma unroll
        for (int k = 0; k < 12; ++k) s += x[k] * sW1[k*16 + j];
        h1[j] = eluf(s);
    }
    float h2[16];
#pragma unroll
    for (int j = 0; j < 16; ++j) {
        float s = sb2[j];
#pragma unroll
        for (int k = 0; k < 16; ++k) s += h1[k] * sW2[k*16 + j];
        h2[j] = eluf(s);
    }
    float o[4];
#pragma unroll
    for (int j = 0; j < 4; ++j) {
        float s = sb3[j];
#pragma unroll
        for (int k = 0; k < 16; ++k) s += h2[k] * sW3[k*4 + j];
        o[j] = s;
    }

    int b = idx / NPTS;
    int icx = (int)cx, icy = (int)cy, icz = (int)cz;
    int flat = (icx * G + icy) * G + icz;
    int base = (b * 12 + set * 4) * G3 + flat;
#pragma unroll
    for (int c = 0; c < 4; ++c) {
        float v = o[c];
        if (v > 0.0f) {
            // grid init is 0; non-negative floats order like uints
            atomicMax((unsigned int*)&scenes[base + c * G3], __float_as_uint(v));
        }
    }
}

// ---------------------------------------------------------------------------
// conv1: [B,12,15,15,15] -> [B,8,8,8,8], k=5, stride=2, pad=2, + bias
// grid: 32 blocks (b,co), 512 threads = one output each
// ---------------------------------------------------------------------------
__global__ __launch_bounds__(512)
void conv1_kernel(const float* __restrict__ scenes,
                  const float* __restrict__ w,    // [8,12,5,5,5]
                  const float* __restrict__ bias, // [8]
                  float* __restrict__ y)          // [B,8,8,8,8]
{
    __shared__ float ws[12*125];
    int b  = blockIdx.x >> 3;
    int co = blockIdx.x & 7;
    for (int i = threadIdx.x; i < 12*125; i += 512) ws[i] = w[co*12*125 + i];
    __syncthreads();

    int t = threadIdx.x;
    int ow = t & 7, oh = (t >> 3) & 7, od = t >> 6;

    float s = bias[co];
    for (int ci = 0; ci < 12; ++ci) {
        const float* sc = scenes + (b*12 + ci) * G3;
        const float* wc = ws + ci * 125;
#pragma unroll
        for (int kd = 0; kd < 5; ++kd) {
            int id = od*2 - 2 + kd;
            if ((unsigned)id >= (unsigned)G) continue;
#pragma unroll
            for (int kh = 0; kh < 5; ++kh) {
                int ih = oh*2 - 2 + kh;
                if ((unsigned)ih >= (unsigned)G) continue;
#pragma unroll
                for (int kw = 0; kw < 5; ++kw) {
                    int iw = ow*2 - 2 + kw;
                    if ((unsigned)iw >= (unsigned)G) continue;
                    s += sc[(id*G + ih)*G + iw] * wc[kd*25 + kh*5 + kw];
                }
            }
        }
    }
    y[(b*8 + co) * 512 + t] = s;
}

// ---------------------------------------------------------------------------
// conv_s: [B,8,8,8,8] -> [B,8,8,8,8], k=5, stride=1, pad=2, + bias
// grid: 32 blocks (b,co), 512 threads; stage x[b] and w[co] in LDS
// ---------------------------------------------------------------------------
__global__ __launch_bounds__(512)
void conv_s_kernel(const float* __restrict__ x,    // [B,8,8,8,8] (post BN+ELU)
                   const float* __restrict__ w,    // [8,8,5,5,5] (this layer)
                   const float* __restrict__ bias, // [8] (this layer)
                   float* __restrict__ y)
{
    __shared__ float xs[8*512];   // 16 KB
    __shared__ float ws[8*125];
    int b  = blockIdx.x >> 3;
    int co = blockIdx.x & 7;
    for (int i = threadIdx.x; i < 8*512; i += 512) xs[i] = x[b*4096 + i];
    for (int i = threadIdx.x; i < 8*125; i += 512) ws[i] = w[co*1000 + i];
    __syncthreads();

    int t = threadIdx.x;
    int ow = t & 7, oh = (t >> 3) & 7, od = t >> 6;

    float s = bias[co];
#pragma unroll
    for (int ci = 0; ci < 8; ++ci) {
        const float* xc = xs + ci * 512;
        const float* wc = ws + ci * 125;
#pragma unroll
        for (int kd = 0; kd < 5; ++kd) {
            int id = od - 2 + kd;
            if ((unsigned)id >= 8u) continue;
#pragma unroll
            for (int kh = 0; kh < 5; ++kh) {
                int ih = oh - 2 + kh;
                if ((unsigned)ih >= 8u) continue;
#pragma unroll
                for (int kw = 0; kw < 5; ++kw) {
                    int iw = ow - 2 + kw;
                    if ((unsigned)iw >= 8u) continue;
                    s += xc[id*64 + ih*8 + iw] * wc[kd*25 + kh*5 + kw];
                }
            }
        }
    }
    y[(b*8 + co) * 512 + t] = s;
}

// ---------------------------------------------------------------------------
// BN (training-mode batch stats over (B,D,H,W)) + affine + ELU
// single block of 256 threads; y: [B,8,512] -> xout same layout
// ---------------------------------------------------------------------------
__global__ __launch_bounds__(256)
void bn_apply_kernel(const float* __restrict__ y,
                     const float* __restrict__ gamma,
                     const float* __restrict__ beta,
                     float* __restrict__ xout)
{
    __shared__ float partial[8];
    __shared__ float sc[8], sh[8];
    int tid = threadIdx.x;
    int wave = tid >> 6, lane = tid & 63;

    for (int c = 0; c < 8; ++c) {
        float sum = 0.f, sq = 0.f;
        for (int e = tid; e < 2048; e += 256) {
            int bb = e >> 9, s = e & 511;
            float v = y[bb*4096 + c*512 + s];
            sum += v; sq += v*v;
        }
#pragma unroll
        for (int o = 32; o > 0; o >>= 1) {
            sum += __shfl_down(sum, o, 64);
            sq  += __shfl_down(sq,  o, 64);
        }
        if (lane == 0) { partial[wave] = sum; partial[4 + wave] = sq; }
        __syncthreads();
        if (tid == 0) {
            float S = partial[0] + partial[1] + partial[2] + partial[3];
            float Q = partial[4] + partial[5] + partial[6] + partial[7];
            float m  = S * (1.0f / 2048.0f);
            float vv = Q * (1.0f / 2048.0f) - m * m;
            float rs = rsqrtf(vv + 1e-5f);
            float scale = gamma[c] * rs;
            sc[c] = scale;
            sh[c] = beta[c] - m * scale;
        }
        __syncthreads();
    }

    for (int i = tid; i < YELEMS; i += 256) {
        int c = (i >> 9) & 7;
        float v = y[i] * sc[c] + sh[c];
        xout[i] = v > 0.f ? v : expm1f(v);
    }
}

// ---------------------------------------------------------------------------
extern "C" void kernel_launch(void* const* d_in, const int* in_sizes, int n_in,
                              void* d_out, int out_size, void* d_ws, size_t ws_size,
                              hipStream_t stream)
{
    const float* goals       = (const float*)d_in[0];
    const float* inputs      = (const float*)d_in[1];
    const float* backgrounds = (const float*)d_in[2];
    const float* W1 = (const float*)d_in[3];
    const float* b1 = (const float*)d_in[4];
    const float* W2 = (const float*)d_in[5];
    const float* b2 = (const float*)d_in[6];
    const float* W3 = (const float*)d_in[7];
    const float* b3 = (const float*)d_in[8];
    const float* conv1_w = (const float*)d_in[9];
    const float* conv1_b = (const float*)d_in[10];
    const float* bn1_g   = (const float*)d_in[11];
    const float* bn1_b   = (const float*)d_in[12];
    const float* convs_w = (const float*)d_in[13]; // [6,8,8,5,5,5]
    const float* convs_b = (const float*)d_in[14]; // [6,8]
    const float* bns_g   = (const float*)d_in[15]; // [6,8]
    const float* bns_b   = (const float*)d_in[16]; // [6,8]

    float* ws     = (float*)d_ws;
    float* scenes = ws;                      // 162000 floats = [4,12,3375]
    float* ybuf   = ws + 162000;             // 16384
    float* xbuf   = ws + 162000 + 16384;     // 16384

    // zero-init scatter grid (ws is poisoned 0xAA before every call)
    hipMemsetAsync(scenes, 0, (size_t)(B * 12 * G3) * sizeof(float), stream);

    // stage 1: points -> features -> scatter-max
    dim3 pgrid((B * NPTS + 255) / 256, 3);
    point_kernel<<<pgrid, 256, 0, stream>>>(inputs, goals, backgrounds,
                                            W1, b1, W2, b2, W3, b3, scenes);

    // stage 2: conv stack
    conv1_kernel<<<32, 512, 0, stream>>>(scenes, conv1_w, conv1_b, ybuf);
    bn_apply_kernel<<<1, 256, 0, stream>>>(ybuf, bn1_g, bn1_b, xbuf);

    for (int i = 0; i < 6; ++i) {
        conv_s_kernel<<<32, 512, 0, stream>>>(xbuf, convs_w + i*8000, convs_b + i*8, ybuf);
        float* dst = (i == 5) ? (float*)d_out : xbuf;
        bn_apply_kernel<<<1, 256, 0, stream>>>(ybuf, bns_g + i*8, bns_b + i*8, dst);
    }
}